// Round 15
// baseline (366.709 us; speedup 1.0000x reference)
//
#include <hip/hip_runtime.h>

typedef __attribute__((ext_vector_type(8))) short short8;
typedef __attribute__((ext_vector_type(4))) float f32x4;

#define THREADS 512

__device__ __forceinline__ float b2f(unsigned short u) {
  return __uint_as_float(((unsigned int)u) << 16);
}
__device__ __forceinline__ unsigned short f2b(float f) {
  unsigned int i = __float_as_uint(f);
  unsigned int r = (i + 0x7fffu + ((i >> 16) & 1u)) >> 16;
  return (unsigned short)r;
}
__device__ __forceinline__ unsigned int cvt_pk_bf16(float lo, float hi) {
  unsigned int r;
  asm volatile("v_cvt_pk_bf16_f32 %0, %1, %2" : "=v"(r) : "v"(lo), "v"(hi));
  return r;
}
// single-value bf16 convert in ONE VALU op (low half of cvt_pk); RNE like f2b
__device__ __forceinline__ unsigned short f2b1(float f) {
  return (unsigned short)cvt_pk_bf16(f, f);
}
__device__ __forceinline__ void unpack2(unsigned int u, float& a, float& b) {
  a = __uint_as_float(u << 16);
  b = __uint_as_float(u & 0xffff0000u);
}
// row-dependent 2-bit swizzle for 64B-row A-fragment tiles
__device__ __forceinline__ unsigned int s2f(unsigned int r) {
  return (r + (r >> 2)) & 3u;
}

// ---------------- pack kernel ----------------
// Bpack slot order (per-wave pair-friendly):
//   slot g_slot = w*7+ng ; gcol(w,ng):
//     ng<4 : pr = 2w+(ng>>1); gcol = 8*(pr>>2) + (pr&3) + (ng&1)*4   (e0 pairs e,e+1)
//     ng>=4: gcol = 32 + 3w + (ng-4)                                  (gate groups)
// Bpack[((g_slot*8+ks)*64+lane)*8+j] = Wcat[d=ks*32+(lane>>4)*8+j][col=gcol*16+(lane&15)]
//   Wcat cols: [0,512)=We0 (col=e*64+h), [512,768)=Wg0a, [768,896)=Wg1a
// Bpack2 (e1 B): [(((e*2+ct)*2+ks)*64+lane)*8+j] = We1[e][h=ks*32+(lane>>4)*8+j][k=ct*16+(lane&15)]
// Bpack3T (gate A = Wg^T): [(u*64+lane)*8+j] = (lane&15)<8 ?
//     Wg[u][h=(lane>>4)*8+j][e=lane&15] : 0     (A rows 8..15 zero)
__global__ void pack_kernel(const float* __restrict__ We0,
                            const float* __restrict__ Wg0a,
                            const float* __restrict__ Wg1a,
                            const float* __restrict__ be0,
                            const float* __restrict__ bg0a,
                            const float* __restrict__ bg1a,
                            const float* __restrict__ We1,
                            const float* __restrict__ Wg0b,
                            const float* __restrict__ Wg1b,
                            unsigned short* __restrict__ Bpack,
                            float* __restrict__ bcat,
                            unsigned short* __restrict__ Bpack2,
                            unsigned short* __restrict__ Bpack3) {
  int gid = blockIdx.x * blockDim.x + threadIdx.x;
  if (gid < 229376) {
    int j = gid & 7;
    int lane = (gid >> 3) & 63;
    int ks = (gid >> 9) & 7;
    int g_slot = gid >> 12;
    int w = g_slot / 7;
    int ng = g_slot - w * 7;
    int gcol;
    if (ng < 4) {
      int pr = 2 * w + (ng >> 1);
      gcol = 8 * (pr >> 2) + (pr & 3) + (ng & 1) * 4;
    } else {
      gcol = 32 + 3 * w + (ng - 4);
    }
    int d = ks * 32 + (lane >> 4) * 8 + j;
    int col = gcol * 16 + (lane & 15);
    float v;
    if (col < 512) {
      v = We0[((col >> 6) * 256 + d) * 64 + (col & 63)];
    } else if (col < 768) {
      int c = col - 512;
      v = Wg0a[((c >> 5) * 256 + d) * 32 + (c & 31)];
    } else {
      int c = col - 768;
      v = Wg1a[((c >> 5) * 256 + d) * 32 + (c & 31)];
    }
    Bpack[gid] = f2b(v);
    if (gid < 896) {
      float bv;
      if (gid < 512) bv = be0[gid];
      else if (gid < 768) bv = bg0a[gid - 512];
      else bv = bg1a[gid - 768];
      bcat[gid] = bv;
    }
  } else if (gid < 245760) {
    int i = gid - 229376;           // 0..16383
    int j = i & 7;
    int lane = (i >> 3) & 63;
    int ks = (i >> 9) & 1;
    int ct = (i >> 10) & 1;
    int e = i >> 11;
    int h = ks * 32 + (lane >> 4) * 8 + j;
    int k = ct * 16 + (lane & 15);
    Bpack2[i] = f2b(We1[(e * 64 + h) * 32 + k]);
  } else if (gid < 251904) {
    int i = gid - 245760;           // 0..6143
    int j = i & 7;
    int lane = (i >> 3) & 63;
    int u = i >> 9;                 // 0..11
    int h = (lane >> 4) * 8 + j;    // hidden index 0..31
    int e = lane & 15;              // A row (expert), 8..15 zero-padded
    float v = 0.f;
    if (e < 8) {
      v = (u < 8) ? Wg0b[(u * 32 + h) * 8 + e]
                  : Wg1b[((u - 8) * 32 + h) * 8 + e];
    }
    Bpack3[i] = f2b(v);
  }
}

// ---------------- fused kernel (persistent: 512 blocks x 4 tiles) ----------------
// 512 blocks x 512 threads, 4 consecutive 32-row tiles per block.
// LDS = 81152 B -> 2 blocks/CU.  Tiles 1..3: next x tile issued to registers
// during P4 (3 phases of HBM-latency cover), written to xt during P6.
//
// MFMA conventions (16x16x32 bf16):
//   A-frag: lane l supplies A[row=l&15][k=(l>>4)*8+j]
//   B-frag: lane l supplies B[k=(l>>4)*8+j][col=l&15]
//   C/D  : lane l holds  D[row=(l>>4)*4+reg][col=l&15]
__global__ __launch_bounds__(THREADS, 4) void fused_kernel(
    const float* __restrict__ x,
    const unsigned short* __restrict__ Bpack,
    const float* __restrict__ bcat,
    const unsigned short* __restrict__ Bpack2,
    const unsigned short* __restrict__ Bpack3,
    const float* __restrict__ be1,
    const float* __restrict__ bg0b,
    const float* __restrict__ bg1b,
    float* __restrict__ out)
{
  __shared__ __align__(16) struct {
    union {
      struct {
        unsigned short xt[32 * 256];     // x tile bf16 swizzled (P2 input)    16384 B
        unsigned short YgA[12 * 32 * 32];// gate hidden A-frags (epi..P3)      24576 B
      } a;
      unsigned short x1A[8 * 32 * 64];   // x1 A-frags for e1 (P4..P5)         32768 B
    } U;                                  // 40960 B  (xt == x1A[0..16K))
    union {
      unsigned short e0B[16 * 1032];     // e0 B-frags, pair-stride 1032 els   33024 B
      unsigned short e1buf[32 * 274];    // e1 bf16 (P5..P6)                   17536 B
    } A2;
    unsigned short g0L[32 * 72];         // g0 probs bf16 [b][g*8+e], stride 72 4608 B
    unsigned short g1L[32 * 40];         // g1 probs bf16 [b][t*8+e], stride 40 2560 B
  } S;                                    // total 81152 B

  const int tid = threadIdx.x;
  const int bid = blockIdx.x;
  const int lane = tid & 63;
  const int wave = tid >> 6;
  const int lr = lane & 15;
  const int lq = lane >> 4;

  // ---- prologue: tile 0's x -> LDS bf16, XOR-swizzled ----
  {
    const float4* xg = (const float4*)(x + (size_t)(bid * 4) * 32 * 256);
    char* xb = (char*)S.U.a.xt;
#pragma unroll
    for (int i = 0; i < 4; ++i) {
      int idx = tid + i * THREADS;          // float4 index 0..2047
      float4 f = xg[idx];
      int row = idx >> 6;
      unsigned int boff = (unsigned int)(idx & 63) * 8;
      unsigned int u0 = cvt_pk_bf16(f.x, f.y);
      unsigned int u1 = cvt_pk_bf16(f.z, f.w);
      unsigned int addr = ((unsigned int)row * 512 + boff) ^ (((unsigned int)(row & 7)) << 4);
      *(uint2*)(xb + addr) = make_uint2(u0, u1);
    }
  }
  __syncthreads();
  __builtin_amdgcn_sched_barrier(0);

  float4 xr[4];                            // next tile's x (issued P4, written P6)

#pragma unroll 1
  for (int it = 0; it < 4; ++it) {
    const int tile = bid * 4 + it;

    // ---- P2: stage-1 GEMM  [32x896] = relu(x @ Wcat + bcat), two passes ----
    short8 bbB[3][3];                      // pass-B prefetch ring (first 2 pre-issued)
    {
      const char* xb = (const char*)S.U.a.xt;
      const unsigned int sw = ((unsigned int)(lr & 7)) << 4;
      const unsigned int a0base = (unsigned int)lr * 512;
      const unsigned int a1base = (unsigned int)(16 + lr) * 512;
      const unsigned short* bp = Bpack + (size_t)(wave * 7) * 4096 + (size_t)lane * 8;

      // ======== pass A: 4 e0 slots (two (gcol,gcol+4) pairs), depth-2 prefetch ========
      {
        f32x4 acc[2][4];
#pragma unroll
        for (int mt = 0; mt < 2; ++mt)
#pragma unroll
          for (int c = 0; c < 4; ++c) acc[mt][c] = {0.f, 0.f, 0.f, 0.f};

        short8 bb[3][4];
#pragma unroll
        for (int c = 0; c < 4; ++c)
          bb[0][c] = *(const short8*)(bp + (size_t)(c * 8 + 0) * 512);
#pragma unroll
        for (int c = 0; c < 4; ++c)
          bb[1][c] = *(const short8*)(bp + (size_t)(c * 8 + 1) * 512);

        __builtin_amdgcn_s_setprio(1);
#pragma unroll
        for (int ks = 0; ks < 8; ++ks) {
          if (ks < 6) {
            const int nn = (ks + 2) % 3;
#pragma unroll
            for (int c = 0; c < 4; ++c)
              bb[nn][c] = *(const short8*)(bp + (size_t)(c * 8 + ks + 2) * 512);
          }
          const int cur = ks % 3;
          unsigned int ko = (unsigned int)ks * 64 + (unsigned int)lq * 16;
          short8 a0 = *(const short8*)(xb + ((a0base + ko) ^ sw));
          short8 a1 = *(const short8*)(xb + ((a1base + ko) ^ sw));
#pragma unroll
          for (int c = 0; c < 4; ++c) {
            acc[0][c] = __builtin_amdgcn_mfma_f32_16x16x32_bf16(a0, bb[cur][c], acc[0][c], 0, 0, 0);
            acc[1][c] = __builtin_amdgcn_mfma_f32_16x16x32_bf16(a1, bb[cur][c], acc[1][c], 0, 0, 0);
          }
        }
        __builtin_amdgcn_s_setprio(0);

        // pre-issue pass B's first two prefetch buffers (hide L2 under epilogue A)
#pragma unroll
        for (int c = 0; c < 3; ++c)
          bbB[0][c] = *(const short8*)(bp + (size_t)((4 + c) * 8 + 0) * 512);
#pragma unroll
        for (int c = 0; c < 3; ++c)
          bbB[1][c] = *(const short8*)(bp + (size_t)((4 + c) * 8 + 1) * 512);
        __builtin_amdgcn_sched_barrier(0);

        // epilogue A: paired cvt_pk stores into e0B
        char* ebase = (char*)S.A2.e0B;
#pragma unroll
        for (int pi2 = 0; pi2 < 2; ++pi2) {
          int pr = 2 * wave + pi2;             // column-pair index 0..15
          int p2 = pr >> 2, n = pr & 3;
          int e_even = 2 * p2;
          int gA = 8 * p2 + n;                 // gcolA ; gcolB = gA+4
          float biasA = bcat[gA * 16 + lr];
          float biasB = bcat[(gA + 4) * 16 + lr];
#pragma unroll
          for (int mt = 0; mt < 2; ++mt) {
#pragma unroll
            for (int rg = 0; rg < 4; ++rg) {
              int b = mt * 16 + lq * 4 + rg;
              float va = fmaxf(acc[mt][pi2 * 2 + 0][rg] + biasA, 0.f);
              float vb = fmaxf(acc[mt][pi2 * 2 + 1][rg] + biasB, 0.f);
              unsigned int pk = cvt_pk_bf16(va, vb);
              *(unsigned int*)(ebase + (b >> 1) * 2064 + (b & 1) * 256 + n * 512 +
                               lr * 16 + e_even * 2) = pk;
            }
          }
        }
      }

      // ======== pass B: 3 gate slots, depth-2 prefetch (ring pre-warmed) ========
      {
        f32x4 acc3[2][3];
#pragma unroll
        for (int mt = 0; mt < 2; ++mt)
#pragma unroll
          for (int c = 0; c < 3; ++c) acc3[mt][c] = {0.f, 0.f, 0.f, 0.f};

        __builtin_amdgcn_s_setprio(1);
#pragma unroll
        for (int ks = 0; ks < 8; ++ks) {
          if (ks < 6) {
            const int nn = (ks + 2) % 3;
#pragma unroll
            for (int c = 0; c < 3; ++c)
              bbB[nn][c] = *(const short8*)(bp + (size_t)((4 + c) * 8 + ks + 2) * 512);
          }
          const int cur = ks % 3;
          unsigned int ko = (unsigned int)ks * 64 + (unsigned int)lq * 16;
          short8 a0 = *(const short8*)(xb + ((a0base + ko) ^ sw));
          short8 a1 = *(const short8*)(xb + ((a1base + ko) ^ sw));
#pragma unroll
          for (int c = 0; c < 3; ++c) {
            acc3[0][c] = __builtin_amdgcn_mfma_f32_16x16x32_bf16(a0, bbB[cur][c], acc3[0][c], 0, 0, 0);
            acc3[1][c] = __builtin_amdgcn_mfma_f32_16x16x32_bf16(a1, bbB[cur][c], acc3[1][c], 0, 0, 0);
          }
        }
        __builtin_amdgcn_s_setprio(0);
        __builtin_amdgcn_sched_barrier(0);

        // epilogue B: YgA u16 scatter (swizzled A-frag layout), 1-op converts
#pragma unroll
        for (int i3 = 0; i3 < 3; ++i3) {
          int gcol = 32 + 3 * wave + i3;
          float bias = bcat[gcol * 16 + lr];
          int c2 = gcol - 32;                  // 0..23
          int u = c2 >> 1;
          int h = (c2 & 1) * 16 + lr;          // 0..31
          int kqw = h >> 3;
          int jw = h & 7;
#pragma unroll
          for (int mt = 0; mt < 2; ++mt) {
#pragma unroll
            for (int rg = 0; rg < 4; ++rg) {
              int row = mt * 16 + lq * 4 + rg;
              float v = fmaxf(acc3[mt][i3][rg] + bias, 0.f);
              S.U.a.YgA[u * 1024 + row * 32 + ((kqw ^ (int)s2f((unsigned int)row)) << 3) + jw] =
                  f2b1(v);
            }
          }
        }
      }
    }

    // pre-issue P3's gate-A fragments (Wg^T; complete by the barrier's vmcnt drain)
    short8 bf3[3];
#pragma unroll
    for (int i = 0; i < 3; ++i) {
      int id = wave * 3 + i;
      int u = id >> 1;
      bf3[i] = *(const short8*)(Bpack3 + (size_t)(u * 64 + lane) * 8);
    }
    __syncthreads();
    __builtin_amdgcn_sched_barrier(0);

    // ---- P3: gate logits via transposed MFMA  D[row=e][col=b]  + in-lane softmax ----
    // item id = u*2 + mtq; wave handles ids 3w..3w+2 (24 items total).
    // Lane holds logits for e = lq*4+reg (valid lq<2), batch row b = mtq*16+lr.
    {
#pragma unroll
      for (int i = 0; i < 3; ++i) {
        int id = wave * 3 + i;
        int u = id >> 1;
        int mtq = id & 1;
        int row = lr + mtq * 16;           // batch row of the B operand
        const char* yb = (const char*)S.U.a.YgA;
        short8 bfB = *(const short8*)(yb + u * 2048 + row * 64 +
                                      ((((unsigned int)lq) ^ s2f((unsigned int)row)) << 4));
        f32x4 dl = {0.f, 0.f, 0.f, 0.f};
        dl = __builtin_amdgcn_mfma_f32_16x16x32_bf16(bf3[i], bfB, dl, 0, 0, 0);

        // bias for e = lq*4+reg (clamped for lq>=2 lanes; their result is unused)
        int bidx = (u < 8 ? u : u - 8) * 8 + (lq & 1) * 4;
        float4 bv = (u < 8) ? *(const float4*)(bg0b + bidx)
                            : *(const float4*)(bg1b + bidx);
        float lg0 = dl[0] + bv.x, lg1 = dl[1] + bv.y;
        float lg2 = dl[2] + bv.z, lg3 = dl[3] + bv.w;
        float m = fmaxf(fmaxf(lg0, lg1), fmaxf(lg2, lg3));
        m = fmaxf(m, __shfl_xor(m, 16));
        float x0 = __expf(lg0 - m), x1 = __expf(lg1 - m);
        float x2 = __expf(lg2 - m), x3 = __expf(lg3 - m);
        float s = (x0 + x1) + (x2 + x3);
        s += __shfl_xor(s, 16);
        float inv = 1.f / s;
        if (lq < 2) {
          unsigned int pk0 = cvt_pk_bf16(x0 * inv, x1 * inv);
          unsigned int pk1 = cvt_pk_bf16(x2 * inv, x3 * inv);
          int b = mtq * 16 + lr;
          unsigned short* dst = (u < 8) ? &S.g0L[b * 72 + u * 8 + lq * 4]
                                        : &S.g1L[b * 40 + (u - 8) * 8 + lq * 4];
          *(unsigned int*)dst = pk0;
          *(unsigned int*)(dst + 2) = pk1;
        }
      }
    }
    __syncthreads();
    __builtin_amdgcn_sched_barrier(0);

    // ---- P4: x1 = g0 @ e0 via block-diagonal MFMA ----
    // pair p (rows 2p,2p+1): A(16x32): A[(bi*8+g)][bi'*8+e] = (bi==bi') g0[2p+bi][g][e]
    // B = e0B[p][n];  D[row=(bi*8+g)][col=hcol] = x1[2p+bi][g][n*16+hcol]
    short8 b2r[4];                         // P5 fragments, pre-issued in P4 tail
    {
      f32x4 xacc[2][4];
#pragma unroll
      for (int pi = 0; pi < 2; ++pi)
#pragma unroll
        for (int n = 0; n < 4; ++n) xacc[pi][n] = {0.f, 0.f, 0.f, 0.f};

      const short8 zero8 = {0, 0, 0, 0, 0, 0, 0, 0};
      const char* e0b = (const char*)S.A2.e0B;
#pragma unroll
      for (int pi = 0; pi < 2; ++pi) {
        int p = wave * 2 + pi;
        int kqh = lq & 1;
        int rtop = lr >> 3;
        int g = lane & 7;
        short8 ga = *(const short8*)&S.g0L[(2 * p + kqh) * 72 + g * 8];
        bool sel = (lane < 32) && (rtop == kqh);
        ga = sel ? ga : zero8;
#pragma unroll
        for (int n = 0; n < 4; ++n) {
          short8 bb = *(const short8*)(e0b + p * 2064 + n * 512 + (lane & 31) * 16);
          xacc[pi][n] = __builtin_amdgcn_mfma_f32_16x16x32_bf16(ga, bb, xacc[pi][n], 0, 0, 0);
        }
      }

      // pre-issue P5's Bpack2 fragments + NEXT tile's x loads
      // (both hide HBM/L2 latency under the x1 writeout + following phases)
#pragma unroll
      for (int ct = 0; ct < 2; ++ct)
#pragma unroll
        for (int k2 = 0; k2 < 2; ++k2)
          b2r[ct * 2 + k2] =
              *(const short8*)(Bpack2 + (size_t)(wave * 4 + ct * 2 + k2) * 512 + lane * 8);
      if (it < 3) {
        const float4* xg = (const float4*)(x + (size_t)(tile + 1) * 32 * 256);
#pragma unroll
        for (int i = 0; i < 4; ++i) xr[i] = xg[tid + i * THREADS];
      }

      // write x1 -> x1A (bf16 A-frags for e1): element (E=g, b, h) at
      // byte = E*4096 + b*128 + ((chunk)<<4) + (h&7)*2,
      // chunk = (h>>3) ^ (b&7) ^ (((g>>2)&1)<<1)   (g-bit spreads write banks)
      char* x1b = (char*)S.U.x1A;
#pragma unroll
      for (int pi = 0; pi < 2; ++pi) {
        int p = wave * 2 + pi;
#pragma unroll
        for (int n = 0; n < 4; ++n) {
#pragma unroll
          for (int reg = 0; reg < 4; ++reg) {
            int row16 = lq * 4 + reg;
            int bi = row16 >> 3, g = row16 & 7;
            int b = 2 * p + bi;
            int h = n * 16 + lr;
            unsigned int chunk = ((unsigned int)(h >> 3)) ^ ((unsigned int)b & 7) ^
                                 ((((unsigned int)g >> 2) & 1) << 1);
            *(unsigned short*)(x1b + g * 4096 + b * 128 + (chunk << 4) +
                               (h & 7) * 2) = f2b1(xacc[pi][n][reg]);
          }
        }
      }
    }
    __syncthreads();
    __builtin_amdgcn_sched_barrier(0);

    // ---- P5: e1 = relu(x1 @ We1 + be1) via MFMA.  wave w = expert w ----
    {
      const int w = wave;
      f32x4 eacc[2][2];
#pragma unroll
      for (int mt = 0; mt < 2; ++mt)
#pragma unroll
        for (int ct = 0; ct < 2; ++ct) eacc[mt][ct] = {0.f, 0.f, 0.f, 0.f};

      const char* x1b = (const char*)S.U.x1A;
      const unsigned int gbit = (((unsigned int)w >> 2) & 1) << 1;
#pragma unroll
      for (int ks = 0; ks < 2; ++ks) {
#pragma unroll
        for (int mt = 0; mt < 2; ++mt) {
          int bp_ = lr + 16 * mt;
          unsigned int chunk = (((unsigned int)(ks * 4 + lq)) ^ ((unsigned int)(bp_ & 7))) ^ gbit;
          short8 a = *(const short8*)(x1b + w * 4096 + bp_ * 128 + (chunk << 4));
          eacc[mt][0] = __builtin_amdgcn_mfma_f32_16x16x32_bf16(a, b2r[0 * 2 + ks], eacc[mt][0], 0, 0, 0);
          eacc[mt][1] = __builtin_amdgcn_mfma_f32_16x16x32_bf16(a, b2r[1 * 2 + ks], eacc[mt][1], 0, 0, 0);
        }
      }
      unsigned short* e1buf = S.A2.e1buf;
#pragma unroll
      for (int ct = 0; ct < 2; ++ct) {
        int k = ct * 16 + lr;
        float bias = be1[w * 32 + k];
#pragma unroll
        for (int mt = 0; mt < 2; ++mt) {
#pragma unroll
          for (int rg = 0; rg < 4; ++rg) {
            int row = mt * 16 + lq * 4 + rg;
            float v = fmaxf(eacc[mt][ct][rg] + bias, 0.f);
            e1buf[row * 274 + w * 34 + k] = f2b1(v);
          }
        }
      }
    }
    __syncthreads();
    __builtin_amdgcn_sched_barrier(0);

    // ---- P6: output combine + write next tile's xt (x1A dead past P5 barrier) ----
    {
      if (it < 3) {
        char* xb = (char*)S.U.a.xt;
#pragma unroll
        for (int i = 0; i < 4; ++i) {
          int idx = tid + i * THREADS;
          float4 f = xr[i];
          int row = idx >> 6;
          unsigned int boff = (unsigned int)(idx & 63) * 8;
          unsigned int u0 = cvt_pk_bf16(f.x, f.y);
          unsigned int u1 = cvt_pk_bf16(f.z, f.w);
          unsigned int addr = ((unsigned int)row * 512 + boff) ^
                              (((unsigned int)(row & 7)) << 4);
          *(uint2*)(xb + addr) = make_uint2(u0, u1);
        }
      }
      const int r = tid >> 4;
      const int j = tid & 15;
      const unsigned short* e1buf = S.A2.e1buf;
      short8 gvt[4];
#pragma unroll
      for (int t = 0; t < 4; ++t)
        gvt[t] = *(const short8*)&S.g1L[r * 40 + t * 8];
      float o0[4], o1[4];
#pragma unroll
      for (int t = 0; t < 4; ++t) { o0[t] = 0.f; o1[t] = 0.f; }
#pragma unroll
      for (int q = 0; q < 8; ++q) {
        unsigned int uu = *(const unsigned int*)&e1buf[r * 274 + q * 34 + j * 2];
        float ev0, ev1;
        unpack2(uu, ev0, ev1);
#pragma unroll
        for (int t = 0; t < 4; ++t) {
          float gt = b2f((unsigned short)gvt[t][q]);
          o0[t] += gt * ev0;
          o1[t] += gt * ev1;
        }
      }
      float* op = out + ((size_t)tile * 32 + r) * 128 + j * 2;
#pragma unroll
      for (int t = 0; t < 4; ++t) {
        *(float2*)(op + t * 32) = make_float2(o0[t], o1[t]);
      }
    }
    __syncthreads();   // protects xt (next P2 read) and e0B (next epilogue A write)
    __builtin_amdgcn_sched_barrier(0);
  }
}

extern "C" void kernel_launch(void* const* d_in, const int* in_sizes, int n_in,
                              void* d_out, int out_size, void* d_ws, size_t ws_size,
                              hipStream_t stream) {
  const float* x    = (const float*)d_in[0];
  const float* We0  = (const float*)d_in[1];
  const float* be0  = (const float*)d_in[2];
  const float* We1  = (const float*)d_in[3];
  const float* be1  = (const float*)d_in[4];
  const float* Wg0a = (const float*)d_in[5];
  const float* bg0a = (const float*)d_in[6];
  const float* Wg0b = (const float*)d_in[7];
  const float* bg0b = (const float*)d_in[8];
  const float* Wg1a = (const float*)d_in[9];
  const float* bg1a = (const float*)d_in[10];
  const float* Wg1b = (const float*)d_in[11];
  const float* bg1b = (const float*)d_in[12];

  unsigned short* Bpack  = (unsigned short*)d_ws;
  float*          bcat   = (float*)((char*)d_ws + 458752);
  unsigned short* Bpack2 = (unsigned short*)((char*)d_ws + 462336);
  unsigned short* Bpack3 = (unsigned short*)((char*)d_ws + 495104);

  pack_kernel<<<492, 512, 0, stream>>>(We0, Wg0a, Wg1a, be0, bg0a, bg1a, We1,
                                       Wg0b, Wg1b, Bpack, bcat, Bpack2, Bpack3);
  fused_kernel<<<512, 512, 0, stream>>>(x, Bpack, bcat, Bpack2, Bpack3, be1,
                                        bg0b, bg1b, (float*)d_out);
}

// Round 16
// 69.749 us; speedup vs baseline: 5.2576x; 5.2576x over previous
//
#include <hip/hip_runtime.h>

typedef __attribute__((ext_vector_type(8))) short short8;
typedef __attribute__((ext_vector_type(4))) float f32x4;

#define THREADS 512

__device__ __forceinline__ float b2f(unsigned short u) {
  return __uint_as_float(((unsigned int)u) << 16);
}
__device__ __forceinline__ unsigned short f2b(float f) {
  unsigned int i = __float_as_uint(f);
  unsigned int r = (i + 0x7fffu + ((i >> 16) & 1u)) >> 16;
  return (unsigned short)r;
}
__device__ __forceinline__ unsigned int cvt_pk_bf16(float lo, float hi) {
  unsigned int r;
  asm volatile("v_cvt_pk_bf16_f32 %0, %1, %2" : "=v"(r) : "v"(lo), "v"(hi));
  return r;
}
// single-value bf16 convert in ONE VALU op (low half of cvt_pk); RNE like f2b
__device__ __forceinline__ unsigned short f2b1(float f) {
  return (unsigned short)cvt_pk_bf16(f, f);
}
__device__ __forceinline__ void unpack2(unsigned int u, float& a, float& b) {
  a = __uint_as_float(u << 16);
  b = __uint_as_float(u & 0xffff0000u);
}
// row-dependent 2-bit swizzle for 64B-row A-fragment tiles
__device__ __forceinline__ unsigned int s2f(unsigned int r) {
  return (r + (r >> 2)) & 3u;
}

// ---------------- pack kernel ----------------
// Bpack slot order (per-wave pair-friendly):
//   slot g_slot = w*7+ng ; gcol(w,ng):
//     ng<4 : pr = 2w+(ng>>1); gcol = 8*(pr>>2) + (pr&3) + (ng&1)*4   (e0 pairs e,e+1)
//     ng>=4: gcol = 32 + 3w + (ng-4)                                  (gate groups)
// Bpack[((g_slot*8+ks)*64+lane)*8+j] = Wcat[d=ks*32+(lane>>4)*8+j][col=gcol*16+(lane&15)]
//   Wcat cols: [0,512)=We0 (col=e*64+h), [512,768)=Wg0a, [768,896)=Wg1a
// Bpack2 (e1 B): [(((e*2+ct)*2+ks)*64+lane)*8+j] = We1[e][h=ks*32+(lane>>4)*8+j][k=ct*16+(lane&15)]
// Bpack3T (gate A = Wg^T): [(u*64+lane)*8+j] = (lane&15)<8 ?
//     Wg[u][h=(lane>>4)*8+j][e=lane&15] : 0     (A rows 8..15 zero)
__global__ void pack_kernel(const float* __restrict__ We0,
                            const float* __restrict__ Wg0a,
                            const float* __restrict__ Wg1a,
                            const float* __restrict__ be0,
                            const float* __restrict__ bg0a,
                            const float* __restrict__ bg1a,
                            const float* __restrict__ We1,
                            const float* __restrict__ Wg0b,
                            const float* __restrict__ Wg1b,
                            unsigned short* __restrict__ Bpack,
                            float* __restrict__ bcat,
                            unsigned short* __restrict__ Bpack2,
                            unsigned short* __restrict__ Bpack3) {
  int gid = blockIdx.x * blockDim.x + threadIdx.x;
  if (gid < 229376) {
    int j = gid & 7;
    int lane = (gid >> 3) & 63;
    int ks = (gid >> 9) & 7;
    int g_slot = gid >> 12;
    int w = g_slot / 7;
    int ng = g_slot - w * 7;
    int gcol;
    if (ng < 4) {
      int pr = 2 * w + (ng >> 1);
      gcol = 8 * (pr >> 2) + (pr & 3) + (ng & 1) * 4;
    } else {
      gcol = 32 + 3 * w + (ng - 4);
    }
    int d = ks * 32 + (lane >> 4) * 8 + j;
    int col = gcol * 16 + (lane & 15);
    float v;
    if (col < 512) {
      v = We0[((col >> 6) * 256 + d) * 64 + (col & 63)];
    } else if (col < 768) {
      int c = col - 512;
      v = Wg0a[((c >> 5) * 256 + d) * 32 + (c & 31)];
    } else {
      int c = col - 768;
      v = Wg1a[((c >> 5) * 256 + d) * 32 + (c & 31)];
    }
    Bpack[gid] = f2b(v);
    if (gid < 896) {
      float bv;
      if (gid < 512) bv = be0[gid];
      else if (gid < 768) bv = bg0a[gid - 512];
      else bv = bg1a[gid - 768];
      bcat[gid] = bv;
    }
  } else if (gid < 245760) {
    int i = gid - 229376;           // 0..16383
    int j = i & 7;
    int lane = (i >> 3) & 63;
    int ks = (i >> 9) & 1;
    int ct = (i >> 10) & 1;
    int e = i >> 11;
    int h = ks * 32 + (lane >> 4) * 8 + j;
    int k = ct * 16 + (lane & 15);
    Bpack2[i] = f2b(We1[(e * 64 + h) * 32 + k]);
  } else if (gid < 251904) {
    int i = gid - 245760;           // 0..6143
    int j = i & 7;
    int lane = (i >> 3) & 63;
    int u = i >> 9;                 // 0..11
    int h = (lane >> 4) * 8 + j;    // hidden index 0..31
    int e = lane & 15;              // A row (expert), 8..15 zero-padded
    float v = 0.f;
    if (e < 8) {
      v = (u < 8) ? Wg0b[(u * 32 + h) * 8 + e]
                  : Wg1b[((u - 8) * 32 + h) * 8 + e];
    }
    Bpack3[i] = f2b(v);
  }
}

// ---------------- fused kernel ----------------
// 2048 blocks x 512 threads, 32 rows/block.  LDS = 81152 B -> 2 blocks/CU.
// P3 uses transposed gate MFMA (A=Wg^T, B=gate-hidden) so softmax is in-lane.
// All scalar bf16 stores use the 1-op v_cvt_pk_bf16_f32 (f2b1).
//
// MFMA conventions (16x16x32 bf16):
//   A-frag: lane l supplies A[row=l&15][k=(l>>4)*8+j]
//   B-frag: lane l supplies B[k=(l>>4)*8+j][col=l&15]
//   C/D  : lane l holds  D[row=(l>>4)*4+reg][col=l&15]
__global__ __launch_bounds__(THREADS, 4) void fused_kernel(
    const float* __restrict__ x,
    const unsigned short* __restrict__ Bpack,
    const float* __restrict__ bcat,
    const unsigned short* __restrict__ Bpack2,
    const unsigned short* __restrict__ Bpack3,
    const float* __restrict__ be1,
    const float* __restrict__ bg0b,
    const float* __restrict__ bg1b,
    float* __restrict__ out)
{
  __shared__ __align__(16) struct {
    union {
      struct {
        unsigned short xt[32 * 256];     // x tile bf16 swizzled (P1..P2)      16384 B
        unsigned short YgA[12 * 32 * 32];// gate hidden A-frags (epi..P3)      24576 B
      } a;
      unsigned short x1A[8 * 32 * 64];   // x1 A-frags for e1 (P4..P5)         32768 B
    } U;                                  // 40960 B
    union {
      unsigned short e0B[16 * 1032];     // e0 B-frags, pair-stride 1032 els   33024 B
      unsigned short e1buf[32 * 274];    // e1 bf16 (P5..P6)                   17536 B
    } A2;
    unsigned short g0L[32 * 72];         // g0 probs bf16 [b][g*8+e], stride 72 4608 B
    unsigned short g1L[32 * 40];         // g1 probs bf16 [b][t*8+e], stride 40 2560 B
  } S;                                    // total 81152 B

  const int tid = threadIdx.x;
  const int bid = blockIdx.x;
  const int lane = tid & 63;
  const int wave = tid >> 6;
  const int lr = lane & 15;
  const int lq = lane >> 4;

  // ---- P1: x tile (32x256 fp32) -> LDS bf16, XOR-swizzled ----
  {
    const float4* xg = (const float4*)(x + (size_t)bid * 32 * 256);
    char* xb = (char*)S.U.a.xt;
#pragma unroll
    for (int i = 0; i < 4; ++i) {
      int idx = tid + i * THREADS;          // float4 index 0..2047
      float4 f = xg[idx];
      int row = idx >> 6;
      unsigned int boff = (unsigned int)(idx & 63) * 8;
      unsigned int u0 = cvt_pk_bf16(f.x, f.y);
      unsigned int u1 = cvt_pk_bf16(f.z, f.w);
      unsigned int addr = ((unsigned int)row * 512 + boff) ^ (((unsigned int)(row & 7)) << 4);
      *(uint2*)(xb + addr) = make_uint2(u0, u1);
    }
  }
  __syncthreads();
  __builtin_amdgcn_sched_barrier(0);

  // ---- P2: stage-1 GEMM  [32x896] = relu(x @ Wcat + bcat), two passes ----
  short8 bbB[3][3];                        // pass-B prefetch ring (first 2 pre-issued)
  {
    const char* xb = (const char*)S.U.a.xt;
    const unsigned int sw = ((unsigned int)(lr & 7)) << 4;
    const unsigned int a0base = (unsigned int)lr * 512;
    const unsigned int a1base = (unsigned int)(16 + lr) * 512;
    const unsigned short* bp = Bpack + (size_t)(wave * 7) * 4096 + (size_t)lane * 8;

    // ======== pass A: 4 e0 slots (two (gcol,gcol+4) pairs), depth-2 prefetch ========
    {
      f32x4 acc[2][4];
#pragma unroll
      for (int mt = 0; mt < 2; ++mt)
#pragma unroll
        for (int c = 0; c < 4; ++c) acc[mt][c] = {0.f, 0.f, 0.f, 0.f};

      short8 bb[3][4];
#pragma unroll
      for (int c = 0; c < 4; ++c)
        bb[0][c] = *(const short8*)(bp + (size_t)(c * 8 + 0) * 512);
#pragma unroll
      for (int c = 0; c < 4; ++c)
        bb[1][c] = *(const short8*)(bp + (size_t)(c * 8 + 1) * 512);

      __builtin_amdgcn_s_setprio(1);
#pragma unroll
      for (int ks = 0; ks < 8; ++ks) {
        if (ks < 6) {
          const int nn = (ks + 2) % 3;
#pragma unroll
          for (int c = 0; c < 4; ++c)
            bb[nn][c] = *(const short8*)(bp + (size_t)(c * 8 + ks + 2) * 512);
        }
        const int cur = ks % 3;
        unsigned int ko = (unsigned int)ks * 64 + (unsigned int)lq * 16;
        short8 a0 = *(const short8*)(xb + ((a0base + ko) ^ sw));
        short8 a1 = *(const short8*)(xb + ((a1base + ko) ^ sw));
#pragma unroll
        for (int c = 0; c < 4; ++c) {
          acc[0][c] = __builtin_amdgcn_mfma_f32_16x16x32_bf16(a0, bb[cur][c], acc[0][c], 0, 0, 0);
          acc[1][c] = __builtin_amdgcn_mfma_f32_16x16x32_bf16(a1, bb[cur][c], acc[1][c], 0, 0, 0);
        }
      }
      __builtin_amdgcn_s_setprio(0);

      // pre-issue pass B's first two prefetch buffers (hide L2 under epilogue A)
#pragma unroll
      for (int c = 0; c < 3; ++c)
        bbB[0][c] = *(const short8*)(bp + (size_t)((4 + c) * 8 + 0) * 512);
#pragma unroll
      for (int c = 0; c < 3; ++c)
        bbB[1][c] = *(const short8*)(bp + (size_t)((4 + c) * 8 + 1) * 512);
      __builtin_amdgcn_sched_barrier(0);

      // epilogue A: paired cvt_pk stores into e0B
      char* ebase = (char*)S.A2.e0B;
#pragma unroll
      for (int pi2 = 0; pi2 < 2; ++pi2) {
        int pr = 2 * wave + pi2;             // column-pair index 0..15
        int p2 = pr >> 2, n = pr & 3;
        int e_even = 2 * p2;
        int gA = 8 * p2 + n;                 // gcolA ; gcolB = gA+4
        float biasA = bcat[gA * 16 + lr];
        float biasB = bcat[(gA + 4) * 16 + lr];
#pragma unroll
        for (int mt = 0; mt < 2; ++mt) {
#pragma unroll
          for (int rg = 0; rg < 4; ++rg) {
            int b = mt * 16 + lq * 4 + rg;
            float va = fmaxf(acc[mt][pi2 * 2 + 0][rg] + biasA, 0.f);
            float vb = fmaxf(acc[mt][pi2 * 2 + 1][rg] + biasB, 0.f);
            unsigned int pk = cvt_pk_bf16(va, vb);
            *(unsigned int*)(ebase + (b >> 1) * 2064 + (b & 1) * 256 + n * 512 +
                             lr * 16 + e_even * 2) = pk;
          }
        }
      }
    }

    // ======== pass B: 3 gate slots, depth-2 prefetch (ring pre-warmed) ========
    {
      f32x4 acc3[2][3];
#pragma unroll
      for (int mt = 0; mt < 2; ++mt)
#pragma unroll
        for (int c = 0; c < 3; ++c) acc3[mt][c] = {0.f, 0.f, 0.f, 0.f};

      __builtin_amdgcn_s_setprio(1);
#pragma unroll
      for (int ks = 0; ks < 8; ++ks) {
        if (ks < 6) {
          const int nn = (ks + 2) % 3;
#pragma unroll
          for (int c = 0; c < 3; ++c)
            bbB[nn][c] = *(const short8*)(bp + (size_t)((4 + c) * 8 + ks + 2) * 512);
        }
        const int cur = ks % 3;
        unsigned int ko = (unsigned int)ks * 64 + (unsigned int)lq * 16;
        short8 a0 = *(const short8*)(xb + ((a0base + ko) ^ sw));
        short8 a1 = *(const short8*)(xb + ((a1base + ko) ^ sw));
#pragma unroll
        for (int c = 0; c < 3; ++c) {
          acc3[0][c] = __builtin_amdgcn_mfma_f32_16x16x32_bf16(a0, bbB[cur][c], acc3[0][c], 0, 0, 0);
          acc3[1][c] = __builtin_amdgcn_mfma_f32_16x16x32_bf16(a1, bbB[cur][c], acc3[1][c], 0, 0, 0);
        }
      }
      __builtin_amdgcn_s_setprio(0);
      __builtin_amdgcn_sched_barrier(0);

      // epilogue B: YgA u16 scatter (swizzled A-frag layout), 1-op converts
#pragma unroll
      for (int i3 = 0; i3 < 3; ++i3) {
        int gcol = 32 + 3 * wave + i3;
        float bias = bcat[gcol * 16 + lr];
        int c2 = gcol - 32;                  // 0..23
        int u = c2 >> 1;
        int h = (c2 & 1) * 16 + lr;          // 0..31
        int kqw = h >> 3;
        int jw = h & 7;
#pragma unroll
        for (int mt = 0; mt < 2; ++mt) {
#pragma unroll
          for (int rg = 0; rg < 4; ++rg) {
            int row = mt * 16 + lq * 4 + rg;
            float v = fmaxf(acc3[mt][i3][rg] + bias, 0.f);
            S.U.a.YgA[u * 1024 + row * 32 + ((kqw ^ (int)s2f((unsigned int)row)) << 3) + jw] =
                f2b1(v);
          }
        }
      }
    }
  }

  // pre-issue P3's gate-A fragments (Wg^T; complete by the barrier's vmcnt drain)
  short8 bf3[3];
#pragma unroll
  for (int i = 0; i < 3; ++i) {
    int id = wave * 3 + i;
    int u = id >> 1;
    bf3[i] = *(const short8*)(Bpack3 + (size_t)(u * 64 + lane) * 8);
  }
  __syncthreads();
  __builtin_amdgcn_sched_barrier(0);

  // ---- P3: gate logits via transposed MFMA  D[row=e][col=b]  + in-lane softmax ----
  // item id = u*2 + mtq; wave handles ids 3w..3w+2 (24 items total).
  // Lane holds logits for e = lq*4+reg (valid lq<2), batch row b = mtq*16+lr.
  {
#pragma unroll
    for (int i = 0; i < 3; ++i) {
      int id = wave * 3 + i;
      int u = id >> 1;
      int mtq = id & 1;
      int row = lr + mtq * 16;           // batch row of the B operand
      const char* yb = (const char*)S.U.a.YgA;
      short8 bfB = *(const short8*)(yb + u * 2048 + row * 64 +
                                    ((((unsigned int)lq) ^ s2f((unsigned int)row)) << 4));
      f32x4 dl = {0.f, 0.f, 0.f, 0.f};
      dl = __builtin_amdgcn_mfma_f32_16x16x32_bf16(bf3[i], bfB, dl, 0, 0, 0);

      // bias for e = lq*4+reg (clamped for lq>=2 lanes; their result is unused)
      int bidx = (u < 8 ? u : u - 8) * 8 + (lq & 1) * 4;
      float4 bv = (u < 8) ? *(const float4*)(bg0b + bidx)
                          : *(const float4*)(bg1b + bidx);
      float lg0 = dl[0] + bv.x, lg1 = dl[1] + bv.y;
      float lg2 = dl[2] + bv.z, lg3 = dl[3] + bv.w;
      float m = fmaxf(fmaxf(lg0, lg1), fmaxf(lg2, lg3));
      m = fmaxf(m, __shfl_xor(m, 16));
      float x0 = __expf(lg0 - m), x1 = __expf(lg1 - m);
      float x2 = __expf(lg2 - m), x3 = __expf(lg3 - m);
      float s = (x0 + x1) + (x2 + x3);
      s += __shfl_xor(s, 16);
      float inv = 1.f / s;
      if (lq < 2) {
        unsigned int pk0 = cvt_pk_bf16(x0 * inv, x1 * inv);
        unsigned int pk1 = cvt_pk_bf16(x2 * inv, x3 * inv);
        int b = mtq * 16 + lr;
        unsigned short* dst = (u < 8) ? &S.g0L[b * 72 + u * 8 + lq * 4]
                                      : &S.g1L[b * 40 + (u - 8) * 8 + lq * 4];
        *(unsigned int*)dst = pk0;
        *(unsigned int*)(dst + 2) = pk1;
      }
    }
  }
  __syncthreads();
  __builtin_amdgcn_sched_barrier(0);

  // ---- P4: x1 = g0 @ e0 via block-diagonal MFMA ----
  // pair p (rows 2p,2p+1): A(16x32): A[(bi*8+g)][bi'*8+e] = (bi==bi') g0[2p+bi][g][e]
  // B = e0B[p][n];  D[row=(bi*8+g)][col=hcol] = x1[2p+bi][g][n*16+hcol]
  short8 b2r[4];                           // P5 fragments, pre-issued in P4 tail
  {
    f32x4 xacc[2][4];
#pragma unroll
    for (int pi = 0; pi < 2; ++pi)
#pragma unroll
      for (int n = 0; n < 4; ++n) xacc[pi][n] = {0.f, 0.f, 0.f, 0.f};

    const short8 zero8 = {0, 0, 0, 0, 0, 0, 0, 0};
    const char* e0b = (const char*)S.A2.e0B;
#pragma unroll
    for (int pi = 0; pi < 2; ++pi) {
      int p = wave * 2 + pi;
      int kqh = lq & 1;
      int rtop = lr >> 3;
      int g = lane & 7;
      short8 ga = *(const short8*)&S.g0L[(2 * p + kqh) * 72 + g * 8];
      bool sel = (lane < 32) && (rtop == kqh);
      ga = sel ? ga : zero8;
#pragma unroll
      for (int n = 0; n < 4; ++n) {
        short8 bb = *(const short8*)(e0b + p * 2064 + n * 512 + (lane & 31) * 16);
        xacc[pi][n] = __builtin_amdgcn_mfma_f32_16x16x32_bf16(ga, bb, xacc[pi][n], 0, 0, 0);
      }
    }

    // pre-issue P5's Bpack2 fragments (hide L2 under the x1 writeout + barrier)
#pragma unroll
    for (int ct = 0; ct < 2; ++ct)
#pragma unroll
      for (int k2 = 0; k2 < 2; ++k2)
        b2r[ct * 2 + k2] =
            *(const short8*)(Bpack2 + (size_t)(wave * 4 + ct * 2 + k2) * 512 + lane * 8);

    // write x1 -> x1A (bf16 A-frags for e1): element (E=g, b, h) at
    // byte = E*4096 + b*128 + ((chunk)<<4) + (h&7)*2,
    // chunk = (h>>3) ^ (b&7) ^ (((g>>2)&1)<<1)   (g-bit spreads write banks)
    char* x1b = (char*)S.U.x1A;
#pragma unroll
    for (int pi = 0; pi < 2; ++pi) {
      int p = wave * 2 + pi;
#pragma unroll
      for (int n = 0; n < 4; ++n) {
#pragma unroll
        for (int reg = 0; reg < 4; ++reg) {
          int row16 = lq * 4 + reg;
          int bi = row16 >> 3, g = row16 & 7;
          int b = 2 * p + bi;
          int h = n * 16 + lr;
          unsigned int chunk = ((unsigned int)(h >> 3)) ^ ((unsigned int)b & 7) ^
                               ((((unsigned int)g >> 2) & 1) << 1);
          *(unsigned short*)(x1b + g * 4096 + b * 128 + (chunk << 4) +
                             (h & 7) * 2) = f2b1(xacc[pi][n][reg]);
        }
      }
    }
  }
  __syncthreads();
  __builtin_amdgcn_sched_barrier(0);

  // ---- P5: e1 = relu(x1 @ We1 + be1) via MFMA.  wave w = expert w ----
  {
    const int w = wave;
    f32x4 eacc[2][2];
#pragma unroll
    for (int mt = 0; mt < 2; ++mt)
#pragma unroll
      for (int ct = 0; ct < 2; ++ct) eacc[mt][ct] = {0.f, 0.f, 0.f, 0.f};

    const char* x1b = (const char*)S.U.x1A;
    const unsigned int gbit = (((unsigned int)w >> 2) & 1) << 1;
#pragma unroll
    for (int ks = 0; ks < 2; ++ks) {
#pragma unroll
      for (int mt = 0; mt < 2; ++mt) {
        int bp_ = lr + 16 * mt;
        unsigned int chunk = (((unsigned int)(ks * 4 + lq)) ^ ((unsigned int)(bp_ & 7))) ^ gbit;
        short8 a = *(const short8*)(x1b + w * 4096 + bp_ * 128 + (chunk << 4));
        eacc[mt][0] = __builtin_amdgcn_mfma_f32_16x16x32_bf16(a, b2r[0 * 2 + ks], eacc[mt][0], 0, 0, 0);
        eacc[mt][1] = __builtin_amdgcn_mfma_f32_16x16x32_bf16(a, b2r[1 * 2 + ks], eacc[mt][1], 0, 0, 0);
      }
    }
    unsigned short* e1buf = S.A2.e1buf;
#pragma unroll
    for (int ct = 0; ct < 2; ++ct) {
      int k = ct * 16 + lr;
      float bias = be1[w * 32 + k];
#pragma unroll
      for (int mt = 0; mt < 2; ++mt) {
#pragma unroll
        for (int rg = 0; rg < 4; ++rg) {
          int row = mt * 16 + lq * 4 + rg;
          float v = fmaxf(eacc[mt][ct][rg] + bias, 0.f);
          e1buf[row * 274 + w * 34 + k] = f2b1(v);
        }
      }
    }
  }
  __syncthreads();
  __builtin_amdgcn_sched_barrier(0);

  // ---- P6: out[t][k] = sum_e g1[t][e]*e1[e][k].  thread (r,j) owns k={2j,2j+1}.
  //      Gate probs via short8 vector loads. ----
  {
    const int r = tid >> 4;
    const int j = tid & 15;
    const unsigned short* e1buf = S.A2.e1buf;
    short8 gvt[4];
#pragma unroll
    for (int t = 0; t < 4; ++t)
      gvt[t] = *(const short8*)&S.g1L[r * 40 + t * 8];
    float o0[4], o1[4];
#pragma unroll
    for (int t = 0; t < 4; ++t) { o0[t] = 0.f; o1[t] = 0.f; }
#pragma unroll
    for (int q = 0; q < 8; ++q) {
      unsigned int uu = *(const unsigned int*)&e1buf[r * 274 + q * 34 + j * 2];
      float ev0, ev1;
      unpack2(uu, ev0, ev1);
#pragma unroll
      for (int t = 0; t < 4; ++t) {
        float gt = b2f((unsigned short)gvt[t][q]);
        o0[t] += gt * ev0;
        o1[t] += gt * ev1;
      }
    }
    float* op = out + ((size_t)bid * 32 + r) * 128 + j * 2;
#pragma unroll
    for (int t = 0; t < 4; ++t) {
      *(float2*)(op + t * 32) = make_float2(o0[t], o1[t]);
    }
  }
}

extern "C" void kernel_launch(void* const* d_in, const int* in_sizes, int n_in,
                              void* d_out, int out_size, void* d_ws, size_t ws_size,
                              hipStream_t stream) {
  const float* x    = (const float*)d_in[0];
  const float* We0  = (const float*)d_in[1];
  const float* be0  = (const float*)d_in[2];
  const float* We1  = (const float*)d_in[3];
  const float* be1  = (const float*)d_in[4];
  const float* Wg0a = (const float*)d_in[5];
  const float* bg0a = (const float*)d_in[6];
  const float* Wg0b = (const float*)d_in[7];
  const float* bg0b = (const float*)d_in[8];
  const float* Wg1a = (const float*)d_in[9];
  const float* bg1a = (const float*)d_in[10];
  const float* Wg1b = (const float*)d_in[11];
  const float* bg1b = (const float*)d_in[12];

  unsigned short* Bpack  = (unsigned short*)d_ws;
  float*          bcat   = (float*)((char*)d_ws + 458752);
  unsigned short* Bpack2 = (unsigned short*)((char*)d_ws + 462336);
  unsigned short* Bpack3 = (unsigned short*)((char*)d_ws + 495104);

  pack_kernel<<<492, 512, 0, stream>>>(We0, Wg0a, Wg1a, be0, bg0a, bg1a, We1,
                                       Wg0b, Wg1b, Bpack, bcat, Bpack2, Bpack3);
  fused_kernel<<<2048, 512, 0, stream>>>(x, Bpack, bcat, Bpack2, Bpack3, be1,
                                         bg0b, bg1b, (float*)d_out);
}

// Round 17
// 68.974 us; speedup vs baseline: 5.3166x; 1.0112x over previous
//
#include <hip/hip_runtime.h>

typedef __attribute__((ext_vector_type(8))) short short8;
typedef __attribute__((ext_vector_type(4))) float f32x4;

#define THREADS 512

__device__ __forceinline__ float b2f(unsigned short u) {
  return __uint_as_float(((unsigned int)u) << 16);
}
__device__ __forceinline__ unsigned short f2b(float f) {
  unsigned int i = __float_as_uint(f);
  unsigned int r = (i + 0x7fffu + ((i >> 16) & 1u)) >> 16;
  return (unsigned short)r;
}
__device__ __forceinline__ unsigned int cvt_pk_bf16(float lo, float hi) {
  unsigned int r;
  asm volatile("v_cvt_pk_bf16_f32 %0, %1, %2" : "=v"(r) : "v"(lo), "v"(hi));
  return r;
}
// single-value bf16 convert in ONE VALU op (low half of cvt_pk); RNE like f2b
__device__ __forceinline__ unsigned short f2b1(float f) {
  return (unsigned short)cvt_pk_bf16(f, f);
}
__device__ __forceinline__ void unpack2(unsigned int u, float& a, float& b) {
  a = __uint_as_float(u << 16);
  b = __uint_as_float(u & 0xffff0000u);
}
// row-dependent 2-bit swizzle for 64B-row A-fragment tiles
__device__ __forceinline__ unsigned int s2f(unsigned int r) {
  return (r + (r >> 2)) & 3u;
}
// Barrier that drains ONLY lgkmcnt (LDS visibility) and leaves global loads
// in flight (T4 counted-vmcnt pattern).  Pending vmem at these barriers is
// always private-register prefetch (bb/bf3/b2r) -- no cross-lane hazard.
__device__ __forceinline__ void barrier_lgkm() {
  __builtin_amdgcn_sched_barrier(0);
  asm volatile("s_waitcnt lgkmcnt(0)" ::: "memory");
  __builtin_amdgcn_s_barrier();
  __builtin_amdgcn_sched_barrier(0);
}

// ---------------- pack kernel ----------------
// Bpack slot order (per-wave pair-friendly):
//   slot g_slot = w*7+ng ; gcol(w,ng):
//     ng<4 : pr = 2w+(ng>>1); gcol = 8*(pr>>2) + (pr&3) + (ng&1)*4   (e0 pairs e,e+1)
//     ng>=4: gcol = 32 + 3w + (ng-4)                                  (gate groups)
// Bpack[((g_slot*8+ks)*64+lane)*8+j] = Wcat[d=ks*32+(lane>>4)*8+j][col=gcol*16+(lane&15)]
//   Wcat cols: [0,512)=We0 (col=e*64+h), [512,768)=Wg0a, [768,896)=Wg1a
// Bpack2 (e1 B): [(((e*2+ct)*2+ks)*64+lane)*8+j] = We1[e][h=ks*32+(lane>>4)*8+j][k=ct*16+(lane&15)]
// Bpack3T (gate A = Wg^T): [(u*64+lane)*8+j] = (lane&15)<8 ?
//     Wg[u][h=(lane>>4)*8+j][e=lane&15] : 0     (A rows 8..15 zero)
__global__ void pack_kernel(const float* __restrict__ We0,
                            const float* __restrict__ Wg0a,
                            const float* __restrict__ Wg1a,
                            const float* __restrict__ be0,
                            const float* __restrict__ bg0a,
                            const float* __restrict__ bg1a,
                            const float* __restrict__ We1,
                            const float* __restrict__ Wg0b,
                            const float* __restrict__ Wg1b,
                            unsigned short* __restrict__ Bpack,
                            float* __restrict__ bcat,
                            unsigned short* __restrict__ Bpack2,
                            unsigned short* __restrict__ Bpack3) {
  int gid = blockIdx.x * blockDim.x + threadIdx.x;
  if (gid < 229376) {
    int j = gid & 7;
    int lane = (gid >> 3) & 63;
    int ks = (gid >> 9) & 7;
    int g_slot = gid >> 12;
    int w = g_slot / 7;
    int ng = g_slot - w * 7;
    int gcol;
    if (ng < 4) {
      int pr = 2 * w + (ng >> 1);
      gcol = 8 * (pr >> 2) + (pr & 3) + (ng & 1) * 4;
    } else {
      gcol = 32 + 3 * w + (ng - 4);
    }
    int d = ks * 32 + (lane >> 4) * 8 + j;
    int col = gcol * 16 + (lane & 15);
    float v;
    if (col < 512) {
      v = We0[((col >> 6) * 256 + d) * 64 + (col & 63)];
    } else if (col < 768) {
      int c = col - 512;
      v = Wg0a[((c >> 5) * 256 + d) * 32 + (c & 31)];
    } else {
      int c = col - 768;
      v = Wg1a[((c >> 5) * 256 + d) * 32 + (c & 31)];
    }
    Bpack[gid] = f2b(v);
    if (gid < 896) {
      float bv;
      if (gid < 512) bv = be0[gid];
      else if (gid < 768) bv = bg0a[gid - 512];
      else bv = bg1a[gid - 768];
      bcat[gid] = bv;
    }
  } else if (gid < 245760) {
    int i = gid - 229376;           // 0..16383
    int j = i & 7;
    int lane = (i >> 3) & 63;
    int ks = (i >> 9) & 1;
    int ct = (i >> 10) & 1;
    int e = i >> 11;
    int h = ks * 32 + (lane >> 4) * 8 + j;
    int k = ct * 16 + (lane & 15);
    Bpack2[i] = f2b(We1[(e * 64 + h) * 32 + k]);
  } else if (gid < 251904) {
    int i = gid - 245760;           // 0..6143
    int j = i & 7;
    int lane = (i >> 3) & 63;
    int u = i >> 9;                 // 0..11
    int h = (lane >> 4) * 8 + j;    // hidden index 0..31
    int e = lane & 15;              // A row (expert), 8..15 zero-padded
    float v = 0.f;
    if (e < 8) {
      v = (u < 8) ? Wg0b[(u * 32 + h) * 8 + e]
                  : Wg1b[((u - 8) * 32 + h) * 8 + e];
    }
    Bpack3[i] = f2b(v);
  }
}

// ---------------- fused kernel ----------------
// 2048 blocks x 512 threads, 32 rows/block.  LDS = 81152 B -> 2 blocks/CU.
// P3 uses transposed gate MFMA; barriers with pending register-prefetch use
// lgkm-only drain (barrier_lgkm) so L2 loads stay in flight across them.
//
// MFMA conventions (16x16x32 bf16):
//   A-frag: lane l supplies A[row=l&15][k=(l>>4)*8+j]
//   B-frag: lane l supplies B[k=(l>>4)*8+j][col=l&15]
//   C/D  : lane l holds  D[row=(l>>4)*4+reg][col=l&15]
__global__ __launch_bounds__(THREADS, 4) void fused_kernel(
    const float* __restrict__ x,
    const unsigned short* __restrict__ Bpack,
    const float* __restrict__ bcat,
    const unsigned short* __restrict__ Bpack2,
    const unsigned short* __restrict__ Bpack3,
    const float* __restrict__ be1,
    const float* __restrict__ bg0b,
    const float* __restrict__ bg1b,
    float* __restrict__ out)
{
  __shared__ __align__(16) struct {
    union {
      struct {
        unsigned short xt[32 * 256];     // x tile bf16 swizzled (P1..P2)      16384 B
        unsigned short YgA[12 * 32 * 32];// gate hidden A-frags (epi..P3)      24576 B
      } a;
      unsigned short x1A[8 * 32 * 64];   // x1 A-frags for e1 (P4..P5)         32768 B
    } U;                                  // 40960 B
    union {
      unsigned short e0B[16 * 1032];     // e0 B-frags, pair-stride 1032 els   33024 B
      unsigned short e1buf[32 * 274];    // e1 bf16 (P5..P6)                   17536 B
    } A2;
    unsigned short g0L[32 * 72];         // g0 probs bf16 [b][g*8+e], stride 72 4608 B
    unsigned short g1L[32 * 40];         // g1 probs bf16 [b][t*8+e], stride 40 2560 B
  } S;                                    // total 81152 B

  const int tid = threadIdx.x;
  const int bid = blockIdx.x;
  const int lane = tid & 63;
  const int wave = tid >> 6;
  const int lr = lane & 15;
  const int lq = lane >> 4;

  const unsigned short* bp = Bpack + (size_t)(wave * 7) * 4096 + (size_t)lane * 8;

  // ---- P1: x tile (32x256 fp32) -> LDS bf16, XOR-swizzled ----
  {
    const float4* xg = (const float4*)(x + (size_t)bid * 32 * 256);
    char* xb = (char*)S.U.a.xt;
#pragma unroll
    for (int i = 0; i < 4; ++i) {
      int idx = tid + i * THREADS;          // float4 index 0..2047
      float4 f = xg[idx];
      int row = idx >> 6;
      unsigned int boff = (unsigned int)(idx & 63) * 8;
      unsigned int u0 = cvt_pk_bf16(f.x, f.y);
      unsigned int u1 = cvt_pk_bf16(f.z, f.w);
      unsigned int addr = ((unsigned int)row * 512 + boff) ^ (((unsigned int)(row & 7)) << 4);
      *(uint2*)(xb + addr) = make_uint2(u0, u1);
    }
  }

  // pre-issue pass A's first two B-prefetch buffers BEFORE the barrier;
  // barrier_lgkm leaves them in flight (pass A starts warm).
  short8 bb[3][4];
#pragma unroll
  for (int c = 0; c < 4; ++c)
    bb[0][c] = *(const short8*)(bp + (size_t)(c * 8 + 0) * 512);
#pragma unroll
  for (int c = 0; c < 4; ++c)
    bb[1][c] = *(const short8*)(bp + (size_t)(c * 8 + 1) * 512);

  barrier_lgkm();

  // ---- P2: stage-1 GEMM  [32x896] = relu(x @ Wcat + bcat), two passes ----
  short8 bbB[3][3];                        // pass-B prefetch ring (first 2 pre-issued)
  {
    const char* xb = (const char*)S.U.a.xt;
    const unsigned int sw = ((unsigned int)(lr & 7)) << 4;
    const unsigned int a0base = (unsigned int)lr * 512;
    const unsigned int a1base = (unsigned int)(16 + lr) * 512;

    // ======== pass A: 4 e0 slots (two (gcol,gcol+4) pairs), depth-2 prefetch ========
    {
      f32x4 acc[2][4];
#pragma unroll
      for (int mt = 0; mt < 2; ++mt)
#pragma unroll
        for (int c = 0; c < 4; ++c) acc[mt][c] = {0.f, 0.f, 0.f, 0.f};

      __builtin_amdgcn_s_setprio(1);
#pragma unroll
      for (int ks = 0; ks < 8; ++ks) {
        if (ks < 6) {
          const int nn = (ks + 2) % 3;
#pragma unroll
          for (int c = 0; c < 4; ++c)
            bb[nn][c] = *(const short8*)(bp + (size_t)(c * 8 + ks + 2) * 512);
        }
        const int cur = ks % 3;
        unsigned int ko = (unsigned int)ks * 64 + (unsigned int)lq * 16;
        short8 a0 = *(const short8*)(xb + ((a0base + ko) ^ sw));
        short8 a1 = *(const short8*)(xb + ((a1base + ko) ^ sw));
#pragma unroll
        for (int c = 0; c < 4; ++c) {
          acc[0][c] = __builtin_amdgcn_mfma_f32_16x16x32_bf16(a0, bb[cur][c], acc[0][c], 0, 0, 0);
          acc[1][c] = __builtin_amdgcn_mfma_f32_16x16x32_bf16(a1, bb[cur][c], acc[1][c], 0, 0, 0);
        }
      }
      __builtin_amdgcn_s_setprio(0);

      // pre-issue pass B's first two prefetch buffers (hide L2 under epilogue A)
#pragma unroll
      for (int c = 0; c < 3; ++c)
        bbB[0][c] = *(const short8*)(bp + (size_t)((4 + c) * 8 + 0) * 512);
#pragma unroll
      for (int c = 0; c < 3; ++c)
        bbB[1][c] = *(const short8*)(bp + (size_t)((4 + c) * 8 + 1) * 512);
      __builtin_amdgcn_sched_barrier(0);

      // epilogue A: paired cvt_pk stores into e0B
      char* ebase = (char*)S.A2.e0B;
#pragma unroll
      for (int pi2 = 0; pi2 < 2; ++pi2) {
        int pr = 2 * wave + pi2;             // column-pair index 0..15
        int p2 = pr >> 2, n = pr & 3;
        int e_even = 2 * p2;
        int gA = 8 * p2 + n;                 // gcolA ; gcolB = gA+4
        float biasA = bcat[gA * 16 + lr];
        float biasB = bcat[(gA + 4) * 16 + lr];
#pragma unroll
        for (int mt = 0; mt < 2; ++mt) {
#pragma unroll
          for (int rg = 0; rg < 4; ++rg) {
            int b = mt * 16 + lq * 4 + rg;
            float va = fmaxf(acc[mt][pi2 * 2 + 0][rg] + biasA, 0.f);
            float vb = fmaxf(acc[mt][pi2 * 2 + 1][rg] + biasB, 0.f);
            unsigned int pk = cvt_pk_bf16(va, vb);
            *(unsigned int*)(ebase + (b >> 1) * 2064 + (b & 1) * 256 + n * 512 +
                             lr * 16 + e_even * 2) = pk;
          }
        }
      }
    }

    // ======== pass B: 3 gate slots, depth-2 prefetch (ring pre-warmed) ========
    {
      f32x4 acc3[2][3];
#pragma unroll
      for (int mt = 0; mt < 2; ++mt)
#pragma unroll
        for (int c = 0; c < 3; ++c) acc3[mt][c] = {0.f, 0.f, 0.f, 0.f};

      __builtin_amdgcn_s_setprio(1);
#pragma unroll
      for (int ks = 0; ks < 8; ++ks) {
        if (ks < 6) {
          const int nn = (ks + 2) % 3;
#pragma unroll
          for (int c = 0; c < 3; ++c)
            bbB[nn][c] = *(const short8*)(bp + (size_t)((4 + c) * 8 + ks + 2) * 512);
        }
        const int cur = ks % 3;
        unsigned int ko = (unsigned int)ks * 64 + (unsigned int)lq * 16;
        short8 a0 = *(const short8*)(xb + ((a0base + ko) ^ sw));
        short8 a1 = *(const short8*)(xb + ((a1base + ko) ^ sw));
#pragma unroll
        for (int c = 0; c < 3; ++c) {
          acc3[0][c] = __builtin_amdgcn_mfma_f32_16x16x32_bf16(a0, bbB[cur][c], acc3[0][c], 0, 0, 0);
          acc3[1][c] = __builtin_amdgcn_mfma_f32_16x16x32_bf16(a1, bbB[cur][c], acc3[1][c], 0, 0, 0);
        }
      }
      __builtin_amdgcn_s_setprio(0);
      __builtin_amdgcn_sched_barrier(0);

      // epilogue B: YgA u16 scatter (swizzled A-frag layout), 1-op converts
#pragma unroll
      for (int i3 = 0; i3 < 3; ++i3) {
        int gcol = 32 + 3 * wave + i3;
        float bias = bcat[gcol * 16 + lr];
        int c2 = gcol - 32;                  // 0..23
        int u = c2 >> 1;
        int h = (c2 & 1) * 16 + lr;          // 0..31
        int kqw = h >> 3;
        int jw = h & 7;
#pragma unroll
        for (int mt = 0; mt < 2; ++mt) {
#pragma unroll
          for (int rg = 0; rg < 4; ++rg) {
            int row = mt * 16 + lq * 4 + rg;
            float v = fmaxf(acc3[mt][i3][rg] + bias, 0.f);
            S.U.a.YgA[u * 1024 + row * 32 + ((kqw ^ (int)s2f((unsigned int)row)) << 3) + jw] =
                f2b1(v);
          }
        }
      }
    }
  }

  // pre-issue P3's gate-A fragments (Wg^T); barrier_lgkm keeps them in flight
  short8 bf3[3];
#pragma unroll
  for (int i = 0; i < 3; ++i) {
    int id = wave * 3 + i;
    int u = id >> 1;
    bf3[i] = *(const short8*)(Bpack3 + (size_t)(u * 64 + lane) * 8);
  }
  barrier_lgkm();

  // ---- P3: gate logits via transposed MFMA  D[row=e][col=b]  + in-lane softmax ----
  // item id = u*2 + mtq; wave handles ids 3w..3w+2 (24 items total).
  // Lane holds logits for e = lq*4+reg (valid lq<2), batch row b = mtq*16+lr.
  {
#pragma unroll
    for (int i = 0; i < 3; ++i) {
      int id = wave * 3 + i;
      int u = id >> 1;
      int mtq = id & 1;
      int row = lr + mtq * 16;           // batch row of the B operand
      const char* yb = (const char*)S.U.a.YgA;
      short8 bfB = *(const short8*)(yb + u * 2048 + row * 64 +
                                    ((((unsigned int)lq) ^ s2f((unsigned int)row)) << 4));
      f32x4 dl = {0.f, 0.f, 0.f, 0.f};
      dl = __builtin_amdgcn_mfma_f32_16x16x32_bf16(bf3[i], bfB, dl, 0, 0, 0);

      // bias for e = lq*4+reg (clamped for lq>=2 lanes; their result is unused)
      int bidx = (u < 8 ? u : u - 8) * 8 + (lq & 1) * 4;
      float4 bv = (u < 8) ? *(const float4*)(bg0b + bidx)
                          : *(const float4*)(bg1b + bidx);
      float lg0 = dl[0] + bv.x, lg1 = dl[1] + bv.y;
      float lg2 = dl[2] + bv.z, lg3 = dl[3] + bv.w;
      float m = fmaxf(fmaxf(lg0, lg1), fmaxf(lg2, lg3));
      m = fmaxf(m, __shfl_xor(m, 16));
      float x0 = __expf(lg0 - m), x1 = __expf(lg1 - m);
      float x2 = __expf(lg2 - m), x3 = __expf(lg3 - m);
      float s = (x0 + x1) + (x2 + x3);
      s += __shfl_xor(s, 16);
      float inv = 1.f / s;
      if (lq < 2) {
        unsigned int pk0 = cvt_pk_bf16(x0 * inv, x1 * inv);
        unsigned int pk1 = cvt_pk_bf16(x2 * inv, x3 * inv);
        int b = mtq * 16 + lr;
        unsigned short* dst = (u < 8) ? &S.g0L[b * 72 + u * 8 + lq * 4]
                                      : &S.g1L[b * 40 + (u - 8) * 8 + lq * 4];
        *(unsigned int*)dst = pk0;
        *(unsigned int*)(dst + 2) = pk1;
      }
    }
  }
  __syncthreads();
  __builtin_amdgcn_sched_barrier(0);

  // ---- P4: x1 = g0 @ e0 via block-diagonal MFMA ----
  // pair p (rows 2p,2p+1): A(16x32): A[(bi*8+g)][bi'*8+e] = (bi==bi') g0[2p+bi][g][e]
  // B = e0B[p][n];  D[row=(bi*8+g)][col=hcol] = x1[2p+bi][g][n*16+hcol]
  short8 b2r[4];                           // P5 fragments, pre-issued in P4 tail
  {
    f32x4 xacc[2][4];
#pragma unroll
    for (int pi = 0; pi < 2; ++pi)
#pragma unroll
      for (int n = 0; n < 4; ++n) xacc[pi][n] = {0.f, 0.f, 0.f, 0.f};

    const short8 zero8 = {0, 0, 0, 0, 0, 0, 0, 0};
    const char* e0b = (const char*)S.A2.e0B;
#pragma unroll
    for (int pi = 0; pi < 2; ++pi) {
      int p = wave * 2 + pi;
      int kqh = lq & 1;
      int rtop = lr >> 3;
      int g = lane & 7;
      short8 ga = *(const short8*)&S.g0L[(2 * p + kqh) * 72 + g * 8];
      bool sel = (lane < 32) && (rtop == kqh);
      ga = sel ? ga : zero8;
#pragma unroll
      for (int n = 0; n < 4; ++n) {
        short8 bb2 = *(const short8*)(e0b + p * 2064 + n * 512 + (lane & 31) * 16);
        xacc[pi][n] = __builtin_amdgcn_mfma_f32_16x16x32_bf16(ga, bb2, xacc[pi][n], 0, 0, 0);
      }
    }

    // pre-issue P5's Bpack2 fragments (stay in flight across barrier_lgkm)
#pragma unroll
    for (int ct = 0; ct < 2; ++ct)
#pragma unroll
      for (int k2 = 0; k2 < 2; ++k2)
        b2r[ct * 2 + k2] =
            *(const short8*)(Bpack2 + (size_t)(wave * 4 + ct * 2 + k2) * 512 + lane * 8);

    // write x1 -> x1A (bf16 A-frags for e1): element (E=g, b, h) at
    // byte = E*4096 + b*128 + ((chunk)<<4) + (h&7)*2,
    // chunk = (h>>3) ^ (b&7) ^ (((g>>2)&1)<<1)   (g-bit spreads write banks)
    char* x1b = (char*)S.U.x1A;
#pragma unroll
    for (int pi = 0; pi < 2; ++pi) {
      int p = wave * 2 + pi;
#pragma unroll
      for (int n = 0; n < 4; ++n) {
#pragma unroll
        for (int reg = 0; reg < 4; ++reg) {
          int row16 = lq * 4 + reg;
          int bi = row16 >> 3, g = row16 & 7;
          int b = 2 * p + bi;
          int h = n * 16 + lr;
          unsigned int chunk = ((unsigned int)(h >> 3)) ^ ((unsigned int)b & 7) ^
                               ((((unsigned int)g >> 2) & 1) << 1);
          *(unsigned short*)(x1b + g * 4096 + b * 128 + (chunk << 4) +
                             (h & 7) * 2) = f2b1(xacc[pi][n][reg]);
        }
      }
    }
  }
  barrier_lgkm();

  // ---- P5: e1 = relu(x1 @ We1 + be1) via MFMA.  wave w = expert w ----
  {
    const int w = wave;
    f32x4 eacc[2][2];
#pragma unroll
    for (int mt = 0; mt < 2; ++mt)
#pragma unroll
      for (int ct = 0; ct < 2; ++ct) eacc[mt][ct] = {0.f, 0.f, 0.f, 0.f};

    const char* x1b = (const char*)S.U.x1A;
    const unsigned int gbit = (((unsigned int)w >> 2) & 1) << 1;
#pragma unroll
    for (int ks = 0; ks < 2; ++ks) {
#pragma unroll
      for (int mt = 0; mt < 2; ++mt) {
        int bp_ = lr + 16 * mt;
        unsigned int chunk = (((unsigned int)(ks * 4 + lq)) ^ ((unsigned int)(bp_ & 7))) ^ gbit;
        short8 a = *(const short8*)(x1b + w * 4096 + bp_ * 128 + (chunk << 4));
        eacc[mt][0] = __builtin_amdgcn_mfma_f32_16x16x32_bf16(a, b2r[0 * 2 + ks], eacc[mt][0], 0, 0, 0);
        eacc[mt][1] = __builtin_amdgcn_mfma_f32_16x16x32_bf16(a, b2r[1 * 2 + ks], eacc[mt][1], 0, 0, 0);
      }
    }
    unsigned short* e1buf = S.A2.e1buf;
#pragma unroll
    for (int ct = 0; ct < 2; ++ct) {
      int k = ct * 16 + lr;
      float bias = be1[w * 32 + k];
#pragma unroll
      for (int mt = 0; mt < 2; ++mt) {
#pragma unroll
        for (int rg = 0; rg < 4; ++rg) {
          int row = mt * 16 + lq * 4 + rg;
          float v = fmaxf(eacc[mt][ct][rg] + bias, 0.f);
          e1buf[row * 274 + w * 34 + k] = f2b1(v);
        }
      }
    }
  }
  __syncthreads();
  __builtin_amdgcn_sched_barrier(0);

  // ---- P6: out[t][k] = sum_e g1[t][e]*e1[e][k].  thread (r,j) owns k={2j,2j+1}.
  //      Gate probs via short8 vector loads. ----
  {
    const int r = tid >> 4;
    const int j = tid & 15;
    const unsigned short* e1buf = S.A2.e1buf;
    short8 gvt[4];
#pragma unroll
    for (int t = 0; t < 4; ++t)
      gvt[t] = *(const short8*)&S.g1L[r * 40 + t * 8];
    float o0[4], o1[4];
#pragma unroll
    for (int t = 0; t < 4; ++t) { o0[t] = 0.f; o1[t] = 0.f; }
#pragma unroll
    for (int q = 0; q < 8; ++q) {
      unsigned int uu = *(const unsigned int*)&e1buf[r * 274 + q * 34 + j * 2];
      float ev0, ev1;
      unpack2(uu, ev0, ev1);
#pragma unroll
      for (int t = 0; t < 4; ++t) {
        float gt = b2f((unsigned short)gvt[t][q]);
        o0[t] += gt * ev0;
        o1[t] += gt * ev1;
      }
    }
    float* op = out + ((size_t)bid * 32 + r) * 128 + j * 2;
#pragma unroll
    for (int t = 0; t < 4; ++t) {
      *(float2*)(op + t * 32) = make_float2(o0[t], o1[t]);
    }
  }
}

extern "C" void kernel_launch(void* const* d_in, const int* in_sizes, int n_in,
                              void* d_out, int out_size, void* d_ws, size_t ws_size,
                              hipStream_t stream) {
  const float* x    = (const float*)d_in[0];
  const float* We0  = (const float*)d_in[1];
  const float* be0  = (const float*)d_in[2];
  const float* We1  = (const float*)d_in[3];
  const float* be1  = (const float*)d_in[4];
  const float* Wg0a = (const float*)d_in[5];
  const float* bg0a = (const float*)d_in[6];
  const float* Wg0b = (const float*)d_in[7];
  const float* bg0b = (const float*)d_in[8];
  const float* Wg1a = (const float*)d_in[9];
  const float* bg1a = (const float*)d_in[10];
  const float* Wg1b = (const float*)d_in[11];
  const float* bg1b = (const float*)d_in[12];

  unsigned short* Bpack  = (unsigned short*)d_ws;
  float*          bcat   = (float*)((char*)d_ws + 458752);
  unsigned short* Bpack2 = (unsigned short*)((char*)d_ws + 462336);
  unsigned short* Bpack3 = (unsigned short*)((char*)d_ws + 495104);

  pack_kernel<<<492, 512, 0, stream>>>(We0, Wg0a, Wg1a, be0, bg0a, bg1a, We1,
                                       Wg0b, Wg1b, Bpack, bcat, Bpack2, Bpack3);
  fused_kernel<<<2048, 512, 0, stream>>>(x, Bpack, bcat, Bpack2, Bpack3, be1,
                                         bg0b, bg1b, (float*)d_out);
}